// Round 10
// baseline (233.820 us; speedup 1.0000x reference)
//
#include <hip/hip_runtime.h>

// Inverse 3D DWT (DB4, periodization), (4,256,256,256) fp32.
// pass 1: axis-1 streaming transform, x -> ws (scalar, dense-row-coverage grid,
//         NT loads of x; measured ~6.1 TB/s, at roofline)
// pass 2: fused axis-2 + axis-3 per (b,d1) slice, ws -> out.
//         Tile 32 (d2) x 256 (full d3), float4 staging, LDS stride 260
//         (16B-aligned rows; 260%32=4 keeps column reads at free 2-way).
// Polyphase: y[2m]   = sum_j s[(m+j-3)&127]*a[j] + w[..]*c[j]
//            y[2m+1] = sum_j s[(m+j-3)&127]*b[j] + w[..]*d[j]
// a[j]=h[6-2j], b[j]=h[7-2j], c[j]=h[2j+1], d[j]=-h[2j].
// NOTE: FILT_DECL owns identifiers a0..a3,b0..b3,c0..c3,d0..d3.

#define FILT_DECL(h)                                          \
  const float a0 = h[6], a1 = h[4], a2 = h[2], a3 = h[0];     \
  const float b0 = h[7], b1 = h[5], b2 = h[3], b3 = h[1];     \
  const float c0 = h[1], c1 = h[3], c2 = h[5], c3 = h[7];     \
  const float d0 = -h[0], d1 = -h[2], d2 = -h[4], d3 = -h[6];

#define Y0(s0,s1,s2,s3,w0,w1,w2,w3)                                        \
  fmaf(w3, c3, fmaf(w2, c2, fmaf(w1, c1, fmaf(w0, c0,                      \
  fmaf(s3, a3, fmaf(s2, a2, fmaf(s1, a1, s0 * a0)))))))
#define Y1(s0,s1,s2,s3,w0,w1,w2,w3)                                        \
  fmaf(w3, d3, fmaf(w2, d2, fmaf(w1, d1, fmaf(w0, d0,                      \
  fmaf(s3, b3, fmaf(s2, b2, fmaf(s1, b1, s0 * b0)))))))

// ---------------- pass 1: axis 1 (row stride 65536), scalar, in -> tmp ----
__global__ __launch_bounds__(256) void wav_axis1_s(const float* __restrict__ in,
                                                   float* __restrict__ tmp,
                                                   const float* __restrict__ h) {
  const int inner = blockIdx.x * 256 + threadIdx.x;
  const int m0 = blockIdx.y * 64;
  const size_t base = (size_t)blockIdx.z * (256u * 65536u) + (unsigned)inner;
  const float* __restrict__ ps = in + base;
  const float* __restrict__ pw = in + base + (size_t)128 * 65536;
  float* __restrict__ po = tmp + base;
  FILT_DECL(h)
  float s0 = __builtin_nontemporal_load(&ps[(size_t)((m0 - 3) & 127) * 65536]);
  float s1 = __builtin_nontemporal_load(&ps[(size_t)((m0 - 2) & 127) * 65536]);
  float s2 = __builtin_nontemporal_load(&ps[(size_t)((m0 - 1) & 127) * 65536]);
  float w0 = __builtin_nontemporal_load(&pw[(size_t)((m0 - 3) & 127) * 65536]);
  float w1 = __builtin_nontemporal_load(&pw[(size_t)((m0 - 2) & 127) * 65536]);
  float w2 = __builtin_nontemporal_load(&pw[(size_t)((m0 - 1) & 127) * 65536]);
  for (int m = m0; m < m0 + 64; ++m) {
    const float s3 = __builtin_nontemporal_load(&ps[(size_t)m * 65536]);
    const float w3 = __builtin_nontemporal_load(&pw[(size_t)m * 65536]);
    po[(size_t)(2 * m) * 65536] = Y0(s0, s1, s2, s3, w0, w1, w2, w3);
    po[(size_t)(2 * m + 1) * 65536] = Y1(s0, s1, s2, s3, w0, w1, w2, w3);
    s0 = s1; s1 = s2; s2 = s3;
    w0 = w1; w1 = w2; w2 = w3;
  }
}

// ---------------- pass 2: fused axes 2+3, full-width tile, tmp -> out -----
// Tile 32 (d2) x 256 (d3); staged 38 rows x 256 cols, LDS stride 260.
#define LSTR 260
__global__ __launch_bounds__(512, 8) void wav_t23w(const float* __restrict__ tmp,
                                                   float* __restrict__ out,
                                                   const float* __restrict__ hg) {
  __shared__ __align__(16) float lb[38 * LSTR];  // 39.5 KB
  const int t = threadIdx.x;
  const int d2t = blockIdx.x;                    // 0..7 (32 d2-rows each)
  const size_t slice = blockIdx.y;               // b*256 + d1
  const float* __restrict__ src = tmp + slice * 65536;
  FILT_DECL(hg)
  const int mb2 = 16 * d2t - 3;

  // stage as float4: 38 rows x 64 f4 = 2432 f4; one wave covers one row/iter
#pragma unroll
  for (int k = 0; k < 4; ++k) {
    const int e = t + 512 * k;
    const int i2 = e >> 6, q4 = e & 63;
    const int g2 = (i2 < 19) ? ((mb2 + i2) & 127) : (128 + ((mb2 + i2 - 19) & 127));
    *reinterpret_cast<float4*>(&lb[i2 * LSTR + 4 * q4]) =
        *reinterpret_cast<const float4*>(src + (g2 << 8) + 4 * q4);
  }
  if (t < 384) {
    const int e = t + 2048;
    const int i2 = e >> 6, q4 = e & 63;
    const int g2 = (i2 < 19) ? ((mb2 + i2) & 127) : (128 + ((mb2 + i2 - 19) & 127));
    *reinterpret_cast<float4*>(&lb[i2 * LSTR + 4 * q4]) =
        *reinterpret_cast<const float4*>(src + (g2 << 8) + 4 * q4);
  }
  __syncthreads();

  // axis-2: 256 columns x 2 half-threads; col j = t>>1, pairs p0..p0+7.
  // Dead-slot in-place: pair p writes y0->row p, y1->row 19+p.
  // Safety: both halves of a column are in the same wave (lockstep); the
  // compiler fence pins all LDS reads before any LDS write; columns never
  // span waves, so no cross-wave sharing.
  {
    const int j = t >> 1, p0 = (t & 1) * 8;
    float S[11], W[11];
#pragma unroll
    for (int i = 0; i < 11; ++i) S[i] = lb[(p0 + i) * LSTR + j];
#pragma unroll
    for (int i = 0; i < 11; ++i) W[i] = lb[(19 + p0 + i) * LSTR + j];
    asm volatile("" ::: "memory");               // reads before writes
#pragma unroll
    for (int q = 0; q < 8; ++q) {
      const int p = p0 + q;
      lb[p * LSTR + j]        = Y0(S[q], S[q+1], S[q+2], S[q+3], W[q], W[q+1], W[q+2], W[q+3]);
      lb[(19 + p) * LSTR + j] = Y1(S[q], S[q+1], S[q+2], S[q+3], W[q], W[q+1], W[q+2], W[q+3]);
    }
  }
  __syncthreads();

  // axis-3: r = t>>4 (0..31 local d2 row), 8 pairs starting at m0 = 8*(t&15).
  // Local out row r lives at phys row (r&1 ? 19+(r>>1) : r>>1).
  const int r = t >> 4, m0 = (t & 15) * 8;
  const int prow = ((r & 1) ? (19 + (r >> 1)) : (r >> 1)) * LSTR;
  float S[11], W[11];
#pragma unroll
  for (int i = 0; i < 11; ++i) {
    const int cs = (m0 + i - 3) & 127;
    S[i] = lb[prow + cs];
    W[i] = lb[prow + 128 + cs];
  }
  float* __restrict__ dst = out + slice * 65536
      + (size_t)(32 * d2t + r) * 256 + 16 * (t & 15);
#pragma unroll
  for (int g = 0; g < 4; ++g) {
    float4 y;
    y.x = Y0(S[2*g],   S[2*g+1], S[2*g+2], S[2*g+3], W[2*g],   W[2*g+1], W[2*g+2], W[2*g+3]);
    y.y = Y1(S[2*g],   S[2*g+1], S[2*g+2], S[2*g+3], W[2*g],   W[2*g+1], W[2*g+2], W[2*g+3]);
    y.z = Y0(S[2*g+1], S[2*g+2], S[2*g+3], S[2*g+4], W[2*g+1], W[2*g+2], W[2*g+3], W[2*g+4]);
    y.w = Y1(S[2*g+1], S[2*g+2], S[2*g+3], S[2*g+4], W[2*g+1], W[2*g+2], W[2*g+3], W[2*g+4]);
    *reinterpret_cast<float4*>(dst + 4 * g) = y;
  }
}

// ================= fallback 3-pass (verified round 2) =================
__global__ __launch_bounds__(256) void wav_axis1(const float* __restrict__ in,
                                                 float* __restrict__ out,
                                                 const float* __restrict__ h) {
  const int inner = blockIdx.x * 256 + threadIdx.x;
  const int m0 = blockIdx.y * 64;
  const size_t base = (size_t)blockIdx.z * (256u * 65536u) + (unsigned)inner;
  const float* __restrict__ ps = in + base;
  const float* __restrict__ pw = in + base + (size_t)128 * 65536;
  float* __restrict__ po = out + base;
  FILT_DECL(h)
  float s0 = ps[(size_t)((m0 - 3) & 127) * 65536];
  float s1 = ps[(size_t)((m0 - 2) & 127) * 65536];
  float s2 = ps[(size_t)((m0 - 1) & 127) * 65536];
  float w0 = pw[(size_t)((m0 - 3) & 127) * 65536];
  float w1 = pw[(size_t)((m0 - 2) & 127) * 65536];
  float w2 = pw[(size_t)((m0 - 1) & 127) * 65536];
  for (int m = m0; m < m0 + 64; ++m) {
    const float s3 = ps[(size_t)m * 65536];
    const float w3 = pw[(size_t)m * 65536];
    po[(size_t)(2 * m) * 65536] = Y0(s0, s1, s2, s3, w0, w1, w2, w3);
    po[(size_t)(2 * m + 1) * 65536] = Y1(s0, s1, s2, s3, w0, w1, w2, w3);
    s0 = s1; s1 = s2; s2 = s3;
    w0 = w1; w1 = w2; w2 = w3;
  }
}

__global__ __launch_bounds__(256) void wav_axis2(float* __restrict__ buf,
                                                 const float* __restrict__ h) {
  __shared__ float tile[256][32];
  const int t = threadIdx.x;
  const int c = t & 31;
  const int g = t >> 5;
  const size_t slice = (size_t)(blockIdx.x >> 3);
  const int col0 = (blockIdx.x & 7) * 32;
  float* __restrict__ p = buf + slice * 65536 + col0;
#pragma unroll
  for (int i = 0; i < 32; ++i) {
    const int rr = i * 8 + g;
    tile[rr][c] = p[rr * 256 + c];
  }
  __syncthreads();
  FILT_DECL(h)
  const int m0 = g * 16;
  float s0 = tile[(m0 - 3) & 127][c];
  float s1 = tile[(m0 - 2) & 127][c];
  float s2 = tile[(m0 - 1) & 127][c];
  float w0 = tile[128 + ((m0 - 3) & 127)][c];
  float w1 = tile[128 + ((m0 - 2) & 127)][c];
  float w2 = tile[128 + ((m0 - 1) & 127)][c];
#pragma unroll
  for (int m = m0; m < m0 + 16; ++m) {
    const float s3 = tile[m][c];
    const float w3 = tile[128 + m][c];
    p[(2 * m) * 256 + c] = Y0(s0, s1, s2, s3, w0, w1, w2, w3);
    p[(2 * m + 1) * 256 + c] = Y1(s0, s1, s2, s3, w0, w1, w2, w3);
    s0 = s1; s1 = s2; s2 = s3;
    w0 = w1; w1 = w2; w2 = w3;
  }
}

__global__ __launch_bounds__(256) void wav_axis3(float* __restrict__ buf,
                                                 const float* __restrict__ h) {
  __shared__ float tile[512];
  const int t = threadIdx.x;
  float* __restrict__ p = buf + (size_t)blockIdx.x * 512;
  tile[t] = p[t];
  tile[256 + t] = p[256 + t];
  __syncthreads();
  FILT_DECL(h)
  const int rr = t >> 7;
  const int m = t & 127;
  const float* __restrict__ line = tile + rr * 256;
  const float s0 = line[(m - 3) & 127];
  const float s1 = line[(m - 2) & 127];
  const float s2 = line[(m - 1) & 127];
  const float s3 = line[m];
  const float w0 = line[128 + ((m - 3) & 127)];
  const float w1 = line[128 + ((m - 2) & 127)];
  const float w2 = line[128 + ((m - 1) & 127)];
  const float w3 = line[128 + m];
  float2 y;
  y.x = Y0(s0, s1, s2, s3, w0, w1, w2, w3);
  y.y = Y1(s0, s1, s2, s3, w0, w1, w2, w3);
  *reinterpret_cast<float2*>(p + rr * 256 + 2 * m) = y;
}

extern "C" void kernel_launch(void* const* d_in, const int* in_sizes, int n_in,
                              void* d_out, int out_size, void* d_ws, size_t ws_size,
                              hipStream_t stream) {
  const float* x = (const float*)d_in[0];
  const float* h = (const float*)d_in[1];
  float* out = (float*)d_out;
  const size_t need = (size_t)4 * 256 * 256 * 256 * 4;   // 268 MB intermediate

  if (ws_size >= need) {
    float* tmp = (float*)d_ws;
    wav_axis1_s<<<dim3(256, 2, 4), 256, 0, stream>>>(x, tmp, h);
    wav_t23w<<<dim3(8, 1024), 512, 0, stream>>>(tmp, out, h);
  } else {
    wav_axis1<<<dim3(256, 2, 4), 256, 0, stream>>>(x, out, h);
    wav_axis2<<<dim3(8192), 256, 0, stream>>>(out, h);
    wav_axis3<<<dim3(131072), 256, 0, stream>>>(out, h);
  }
}

// Round 11
// 223.293 us; speedup vs baseline: 1.0471x; 1.0471x over previous
//
#include <hip/hip_runtime.h>

// Inverse 3D DWT (DB4, periodization), (4,256,256,256) fp32.
// pass 1: axis-1 streaming transform, x -> ws (scalar, dense-row-coverage grid,
//         NT loads of x; measured ~6.1 TB/s, at roofline)
// pass 2: fused axis-2 + axis-3 per (b,d1) slice, ws -> out.
//         Tile 32 (d2) x 256 (full d3). Staging via global_load_lds (4B DMA,
//         no VGPR round-trip). LDS layout with 3-col halos so axis-3 reads
//         are aligned vector loads:  [s-halo 0..2 | s 3..130 | pad | w-halo
//         132..134 | w 135..262], stride 264.  phys(c) = c + (c<128 ? 3 : 7).
// Polyphase: y[2m]   = sum_j s[(m+j-3)&127]*a[j] + w[..]*c[j]
//            y[2m+1] = sum_j s[(m+j-3)&127]*b[j] + w[..]*d[j]
// a[j]=h[6-2j], b[j]=h[7-2j], c[j]=h[2j+1], d[j]=-h[2j].
// NOTE: FILT_DECL owns identifiers a0..a3,b0..b3,c0..c3,d0..d3.

#define FILT_DECL(h)                                          \
  const float a0 = h[6], a1 = h[4], a2 = h[2], a3 = h[0];     \
  const float b0 = h[7], b1 = h[5], b2 = h[3], b3 = h[1];     \
  const float c0 = h[1], c1 = h[3], c2 = h[5], c3 = h[7];     \
  const float d0 = -h[0], d1 = -h[2], d2 = -h[4], d3 = -h[6];

#define Y0(s0,s1,s2,s3,w0,w1,w2,w3)                                        \
  fmaf(w3, c3, fmaf(w2, c2, fmaf(w1, c1, fmaf(w0, c0,                      \
  fmaf(s3, a3, fmaf(s2, a2, fmaf(s1, a1, s0 * a0)))))))
#define Y1(s0,s1,s2,s3,w0,w1,w2,w3)                                        \
  fmaf(w3, d3, fmaf(w2, d2, fmaf(w1, d1, fmaf(w0, d0,                      \
  fmaf(s3, b3, fmaf(s2, b2, fmaf(s1, b1, s0 * b0)))))))

// global -> LDS direct DMA, 4 bytes per lane (CK-style addrspace casts)
__device__ __forceinline__ void gload_lds4(const float* g, float* l) {
  auto gp = reinterpret_cast<const __attribute__((address_space(1))) int*>(
      reinterpret_cast<uintptr_t>(g));
  auto lp = reinterpret_cast<__attribute__((address_space(3))) int*>(
      reinterpret_cast<uintptr_t>(l));
  __builtin_amdgcn_global_load_lds(gp, lp, 4, 0, 0);
}

// ---------------- pass 1: axis 1 (row stride 65536), scalar, in -> tmp ----
__global__ __launch_bounds__(256) void wav_axis1_s(const float* __restrict__ in,
                                                   float* __restrict__ tmp,
                                                   const float* __restrict__ h) {
  const int inner = blockIdx.x * 256 + threadIdx.x;
  const int m0 = blockIdx.y * 64;
  const size_t base = (size_t)blockIdx.z * (256u * 65536u) + (unsigned)inner;
  const float* __restrict__ ps = in + base;
  const float* __restrict__ pw = in + base + (size_t)128 * 65536;
  float* __restrict__ po = tmp + base;
  FILT_DECL(h)
  float s0 = __builtin_nontemporal_load(&ps[(size_t)((m0 - 3) & 127) * 65536]);
  float s1 = __builtin_nontemporal_load(&ps[(size_t)((m0 - 2) & 127) * 65536]);
  float s2 = __builtin_nontemporal_load(&ps[(size_t)((m0 - 1) & 127) * 65536]);
  float w0 = __builtin_nontemporal_load(&pw[(size_t)((m0 - 3) & 127) * 65536]);
  float w1 = __builtin_nontemporal_load(&pw[(size_t)((m0 - 2) & 127) * 65536]);
  float w2 = __builtin_nontemporal_load(&pw[(size_t)((m0 - 1) & 127) * 65536]);
  for (int m = m0; m < m0 + 64; ++m) {
    const float s3 = __builtin_nontemporal_load(&ps[(size_t)m * 65536]);
    const float w3 = __builtin_nontemporal_load(&pw[(size_t)m * 65536]);
    po[(size_t)(2 * m) * 65536] = Y0(s0, s1, s2, s3, w0, w1, w2, w3);
    po[(size_t)(2 * m + 1) * 65536] = Y1(s0, s1, s2, s3, w0, w1, w2, w3);
    s0 = s1; s1 = s2; s2 = s3;
    w0 = w1; w1 = w2; w2 = w3;
  }
}

// ---------------- pass 2: fused axes 2+3, halo layout, tmp -> out ---------
#define LSTR 264
__global__ __launch_bounds__(512, 8) void wav_t23h(const float* __restrict__ tmp,
                                                   float* __restrict__ out,
                                                   const float* __restrict__ hg) {
  __shared__ __align__(16) float lb[38 * LSTR];  // 40.1 KB -> 4 blocks/CU
  const int t = threadIdx.x;
  const int d2t = blockIdx.x;                    // 0..7 (32 d2-rows each)
  const size_t slice = blockIdx.y;               // b*256 + d1
  const float* __restrict__ src = tmp + slice * 65536;
  FILT_DECL(hg)
  const int mb2 = 16 * d2t - 3;

  // stage 38 rows x 256 cols via global_load_lds. Within a wave, c spans a
  // 64-aligned window (never crosses c=128), so LDS dest = uniform base +
  // lane*4 as the instruction requires.
#pragma unroll
  for (int k = 0; k < 19; ++k) {
    const int e = t + 512 * k;
    const int i2 = e >> 8, c = e & 255;
    const int g2 = (i2 < 19) ? ((mb2 + i2) & 127) : (128 + ((mb2 + i2 - 19) & 127));
    const int phys = c + ((c < 128) ? 3 : 7);
    gload_lds4(src + (g2 << 8) + c, &lb[i2 * LSTR + phys]);
  }
  __syncthreads();

  // axis-2: 256 columns x 2 half-threads; col j = t>>1, pairs p0..p0+7.
  // Dead-slot in-place: pair p writes y0->row p, y1->row 19+p. The fence is
  // REQUIRED: per-thread alias analysis would otherwise allow a write (row
  // p0+q) to sink above another lane's read of that same row (cross-lane
  // overlap between the p0=0 and p0=8 halves of each column).
  {
    const int j = t >> 1, p0 = (t & 1) * 8;
    const int pj = j + ((j < 128) ? 3 : 7);
    float S[11], W[11];
#pragma unroll
    for (int i = 0; i < 11; ++i) S[i] = lb[(p0 + i) * LSTR + pj];
#pragma unroll
    for (int i = 0; i < 11; ++i) W[i] = lb[(19 + p0 + i) * LSTR + pj];
    asm volatile("" ::: "memory");               // all reads before any write
    // transformed cols 125..127 / 253..255 also duplicated into the halos
    const int hcol = (j >= 125 && j < 128) ? (j - 125)
                   : ((j >= 253) ? (j - 121) : -1);
#pragma unroll
    for (int q = 0; q < 8; ++q) {
      const int p = p0 + q;
      const float y0 = Y0(S[q], S[q+1], S[q+2], S[q+3], W[q], W[q+1], W[q+2], W[q+3]);
      const float y1 = Y1(S[q], S[q+1], S[q+2], S[q+3], W[q], W[q+1], W[q+2], W[q+3]);
      lb[p * LSTR + pj] = y0;
      lb[(19 + p) * LSTR + pj] = y1;
      if (hcol >= 0) {
        lb[p * LSTR + hcol] = y0;
        lb[(19 + p) * LSTR + hcol] = y1;
      }
    }
  }
  __syncthreads();

  // axis-3: r = t>>4 (0..31 local d2 row), 8 pairs starting at m0 = 8*(t&15).
  // Local out row r lives at phys row (r&1 ? 19+(r>>1) : r>>1).
  // Halo layout makes reads contiguous & aligned:
  //   S[i] = lb[prow + m0 + i]        (base 32B-aligned)
  //   W[i] = lb[prow + 132 + m0 + i]  (base 16B-aligned)
  const int r = t >> 4, m0 = (t & 15) * 8;
  const int prow = ((r & 1) ? (19 + (r >> 1)) : (r >> 1)) * LSTR;
  float S[11], W[11];
  {
    const float4 sa = *reinterpret_cast<const float4*>(&lb[prow + m0]);
    const float4 sb = *reinterpret_cast<const float4*>(&lb[prow + m0 + 4]);
    const float2 sc = *reinterpret_cast<const float2*>(&lb[prow + m0 + 8]);
    S[0]=sa.x; S[1]=sa.y; S[2]=sa.z; S[3]=sa.w;
    S[4]=sb.x; S[5]=sb.y; S[6]=sb.z; S[7]=sb.w;
    S[8]=sc.x; S[9]=sc.y; S[10]=lb[prow + m0 + 10];
    const float4 wa = *reinterpret_cast<const float4*>(&lb[prow + 132 + m0]);
    const float4 wb = *reinterpret_cast<const float4*>(&lb[prow + 132 + m0 + 4]);
    const float2 wc = *reinterpret_cast<const float2*>(&lb[prow + 132 + m0 + 8]);
    W[0]=wa.x; W[1]=wa.y; W[2]=wa.z; W[3]=wa.w;
    W[4]=wb.x; W[5]=wb.y; W[6]=wb.z; W[7]=wb.w;
    W[8]=wc.x; W[9]=wc.y; W[10]=lb[prow + 132 + m0 + 10];
  }
  float* __restrict__ dst = out + slice * 65536
      + (size_t)(32 * d2t + r) * 256 + 16 * (t & 15);
#pragma unroll
  for (int g = 0; g < 4; ++g) {
    float4 y;
    y.x = Y0(S[2*g],   S[2*g+1], S[2*g+2], S[2*g+3], W[2*g],   W[2*g+1], W[2*g+2], W[2*g+3]);
    y.y = Y1(S[2*g],   S[2*g+1], S[2*g+2], S[2*g+3], W[2*g],   W[2*g+1], W[2*g+2], W[2*g+3]);
    y.z = Y0(S[2*g+1], S[2*g+2], S[2*g+3], S[2*g+4], W[2*g+1], W[2*g+2], W[2*g+3], W[2*g+4]);
    y.w = Y1(S[2*g+1], S[2*g+2], S[2*g+3], S[2*g+4], W[2*g+1], W[2*g+2], W[2*g+3], W[2*g+4]);
    *reinterpret_cast<float4*>(dst + 4 * g) = y;
  }
}

// ================= fallback 3-pass (verified round 2) =================
__global__ __launch_bounds__(256) void wav_axis1(const float* __restrict__ in,
                                                 float* __restrict__ out,
                                                 const float* __restrict__ h) {
  const int inner = blockIdx.x * 256 + threadIdx.x;
  const int m0 = blockIdx.y * 64;
  const size_t base = (size_t)blockIdx.z * (256u * 65536u) + (unsigned)inner;
  const float* __restrict__ ps = in + base;
  const float* __restrict__ pw = in + base + (size_t)128 * 65536;
  float* __restrict__ po = out + base;
  FILT_DECL(h)
  float s0 = ps[(size_t)((m0 - 3) & 127) * 65536];
  float s1 = ps[(size_t)((m0 - 2) & 127) * 65536];
  float s2 = ps[(size_t)((m0 - 1) & 127) * 65536];
  float w0 = pw[(size_t)((m0 - 3) & 127) * 65536];
  float w1 = pw[(size_t)((m0 - 2) & 127) * 65536];
  float w2 = pw[(size_t)((m0 - 1) & 127) * 65536];
  for (int m = m0; m < m0 + 64; ++m) {
    const float s3 = ps[(size_t)m * 65536];
    const float w3 = pw[(size_t)m * 65536];
    po[(size_t)(2 * m) * 65536] = Y0(s0, s1, s2, s3, w0, w1, w2, w3);
    po[(size_t)(2 * m + 1) * 65536] = Y1(s0, s1, s2, s3, w0, w1, w2, w3);
    s0 = s1; s1 = s2; s2 = s3;
    w0 = w1; w1 = w2; w2 = w3;
  }
}

__global__ __launch_bounds__(256) void wav_axis2(float* __restrict__ buf,
                                                 const float* __restrict__ h) {
  __shared__ float tile[256][32];
  const int t = threadIdx.x;
  const int c = t & 31;
  const int g = t >> 5;
  const size_t slice = (size_t)(blockIdx.x >> 3);
  const int col0 = (blockIdx.x & 7) * 32;
  float* __restrict__ p = buf + slice * 65536 + col0;
#pragma unroll
  for (int i = 0; i < 32; ++i) {
    const int rr = i * 8 + g;
    tile[rr][c] = p[rr * 256 + c];
  }
  __syncthreads();
  FILT_DECL(h)
  const int m0 = g * 16;
  float s0 = tile[(m0 - 3) & 127][c];
  float s1 = tile[(m0 - 2) & 127][c];
  float s2 = tile[(m0 - 1) & 127][c];
  float w0 = tile[128 + ((m0 - 3) & 127)][c];
  float w1 = tile[128 + ((m0 - 2) & 127)][c];
  float w2 = tile[128 + ((m0 - 1) & 127)][c];
#pragma unroll
  for (int m = m0; m < m0 + 16; ++m) {
    const float s3 = tile[m][c];
    const float w3 = tile[128 + m][c];
    p[(2 * m) * 256 + c] = Y0(s0, s1, s2, s3, w0, w1, w2, w3);
    p[(2 * m + 1) * 256 + c] = Y1(s0, s1, s2, s3, w0, w1, w2, w3);
    s0 = s1; s1 = s2; s2 = s3;
    w0 = w1; w1 = w2; w2 = w3;
  }
}

__global__ __launch_bounds__(256) void wav_axis3(float* __restrict__ buf,
                                                 const float* __restrict__ h) {
  __shared__ float tile[512];
  const int t = threadIdx.x;
  float* __restrict__ p = buf + (size_t)blockIdx.x * 512;
  tile[t] = p[t];
  tile[256 + t] = p[256 + t];
  __syncthreads();
  FILT_DECL(h)
  const int rr = t >> 7;
  const int m = t & 127;
  const float* __restrict__ line = tile + rr * 256;
  const float s0 = line[(m - 3) & 127];
  const float s1 = line[(m - 2) & 127];
  const float s2 = line[(m - 1) & 127];
  const float s3 = line[m];
  const float w0 = line[128 + ((m - 3) & 127)];
  const float w1 = line[128 + ((m - 2) & 127)];
  const float w2 = line[128 + ((m - 1) & 127)];
  const float w3 = line[128 + m];
  float2 y;
  y.x = Y0(s0, s1, s2, s3, w0, w1, w2, w3);
  y.y = Y1(s0, s1, s2, s3, w0, w1, w2, w3);
  *reinterpret_cast<float2*>(p + rr * 256 + 2 * m) = y;
}

extern "C" void kernel_launch(void* const* d_in, const int* in_sizes, int n_in,
                              void* d_out, int out_size, void* d_ws, size_t ws_size,
                              hipStream_t stream) {
  const float* x = (const float*)d_in[0];
  const float* h = (const float*)d_in[1];
  float* out = (float*)d_out;
  const size_t need = (size_t)4 * 256 * 256 * 256 * 4;   // 268 MB intermediate

  if (ws_size >= need) {
    float* tmp = (float*)d_ws;
    wav_axis1_s<<<dim3(256, 2, 4), 256, 0, stream>>>(x, tmp, h);
    wav_t23h<<<dim3(8, 1024), 512, 0, stream>>>(tmp, out, h);
  } else {
    wav_axis1<<<dim3(256, 2, 4), 256, 0, stream>>>(x, out, h);
    wav_axis2<<<dim3(8192), 256, 0, stream>>>(out, h);
    wav_axis3<<<dim3(131072), 256, 0, stream>>>(out, h);
  }
}